// Round 8
// baseline (535.644 us; speedup 1.0000x reference)
//
#include <hip/hip_runtime.h>
#include <hip/hip_cooperative_groups.h>

namespace cg = cooperative_groups;

// GCN 2-layer forward — phase-parameterized mega-kernel.
// Coop path: ONE hipLaunchCooperativeKernel running phases 0..8 with
//   grid.sync() between dependent phases; grid = occupancy-query * numCU
//   (R7 failed because hard-coded 512 > runtime's co-residency limit at
//   34.8KB LDS; now LDS<=25856B and grid is validated by construction).
// Fallback path (coop attr/occupancy unavailable): 9 ordinary launches of
//   the same kernel, one phase each (stream order = barrier) ~= R6 perf.
// Phases: 0 zero | 1 hist | 2 scanB | 3 partition | 4 bsort
//         | 5 gemm1(MFMA bf16, 2 col-halves) | 6 pull1 | 7 gemm2 | 8 pull2+lsm

typedef unsigned int uint32;
typedef unsigned short u16;
typedef __attribute__((ext_vector_type(8))) short bf16x8;
typedef __attribute__((ext_vector_type(4))) float f32x4;

#define NBMAX 1024
#define CHUNK 4096
#define SMEM_BYTES 25856   // max phase: gemm2 (16*132*4 + 512 + 32*132*4)

__device__ inline u16 bf16rn(float f) {
    unsigned u = __float_as_uint(f);
    return (u16)((u + 0x7fffu + ((u >> 16) & 1u)) >> 16);
}

__device__ inline void bffma(float2& a, float w, uint32 u) {
    a.x = fmaf(w, __uint_as_float(u << 16), a.x);
    a.y = fmaf(w, __uint_as_float(u & 0xffff0000u), a.y);
}

__global__ __launch_bounds__(256, 2) void k_mega(
    const float* __restrict__ x, const int* __restrict__ src,
    const int* __restrict__ dstv,
    const float* __restrict__ W1, const float* __restrict__ b1,
    const float* __restrict__ W2, const float* __restrict__ b2,
    int* __restrict__ bcnt, int* __restrict__ bbase, int* __restrict__ bfill,
    int* __restrict__ rs, float* __restrict__ dinv,
    int2* __restrict__ tmp, int* __restrict__ ssrc,
    u16* __restrict__ h, uint32* __restrict__ out1,
    float* __restrict__ outp, int N, int E, int NB, int p0, int p1)
{
    __shared__ __align__(16) unsigned char smem[SMEM_BYTES];
    const int t = threadIdx.x;
    const int nbk = gridDim.x;
    const int gtid = blockIdx.x * 256 + t;
    const int gsz = nbk * 256;

    cg::grid_group grid = cg::this_grid();
    #define INPH(p) (p0 <= (p) && (p) <= p1)
    #define GSYNC(p) if (p0 < (p) && (p) <= p1) grid.sync()

    // ---- P0: zero bucket counters -----------------------------------------
    if (INPH(0)) {
        for (int i = gtid; i < NBMAX; i += gsz) bcnt[i] = 0;
    }
    GSYNC(1);

    // ---- P1: coarse bucket histogram (LDS-staged) -------------------------
    if (INPH(1)) {
        int* hl = (int*)smem;
        for (int i = t; i < NB; i += 256) hl[i] = 0;
        __syncthreads();
        for (int e = gtid; e < E; e += gsz) atomicAdd(&hl[dstv[e] >> 8], 1);
        __syncthreads();
        for (int i = t; i < NB; i += 256)
            if (hl[i]) atomicAdd(&bcnt[i], hl[i]);
        __syncthreads();
    }
    GSYNC(2);

    // ---- P2: exclusive scan of bucket counts (block 0) --------------------
    if (INPH(2) && blockIdx.x == 0) {
        int* s = (int*)smem;
        int v[4];
        int sum = 0;
        #pragma unroll
        for (int i = 0; i < 4; ++i) {
            int idx = t * 4 + i;
            v[i] = (idx < NB) ? bcnt[idx] : 0;
            sum += v[i];
        }
        s[t] = sum;
        __syncthreads();
        for (int off = 1; off < 256; off <<= 1) {
            int u = (t >= off) ? s[t - off] : 0;
            __syncthreads();
            s[t] += u;
            __syncthreads();
        }
        int excl = (t > 0) ? s[t - 1] : 0;
        #pragma unroll
        for (int i = 0; i < 4; ++i) {
            int idx = t * 4 + i;
            if (idx < NB) { bbase[idx] = excl; bfill[idx] = 0; }
            excl += v[i];
        }
        if (t == 0) bbase[NB] = E;
        __syncthreads();
    }
    GSYNC(3);

    // ---- P3: partition edges into bucket regions --------------------------
    if (INPH(3)) {
        int* cntL = (int*)smem;
        int* baseL = cntL + NBMAX;
        int nchunk = (E + CHUNK - 1) / CHUNK;
        for (int c = blockIdx.x; c < nchunk; c += nbk) {
            int e0 = c * CHUNK, e1 = min(e0 + CHUNK, E);
            for (int i = t; i < NB; i += 256) cntL[i] = 0;
            __syncthreads();
            for (int e = e0 + t; e < e1; e += 256)
                atomicAdd(&cntL[dstv[e] >> 8], 1);
            __syncthreads();
            for (int i = t; i < NB; i += 256) {
                int cc = cntL[i];
                baseL[i] = cc ? bbase[i] + atomicAdd(&bfill[i], cc) : 0;
                cntL[i] = 0;
            }
            __syncthreads();
            for (int e = e0 + t; e < e1; e += 256) {
                int sv = src[e], d = dstv[e];
                int b = d >> 8;
                int r = atomicAdd(&cntL[b], 1);
                tmp[baseL[b] + r] = make_int2(sv, d);
            }
            __syncthreads();
        }
    }
    GSYNC(4);

    // ---- P4: per-bucket exact sort; emit dinv / rs / ssrc -----------------
    if (INPH(4)) {
        int* cnt = (int*)smem;
        int* ofs = cnt + 256;
        for (int b = blockIdx.x; b < NB; b += nbk) {
            int base = bbase[b];
            int endb = bbase[b + 1];
            int node0 = b << 8;
            cnt[t] = 0;
            __syncthreads();
            for (int i = base + t; i < endb; i += 256)
                atomicAdd(&cnt[tmp[i].y & 255], 1);
            __syncthreads();
            int v = cnt[t];
            __syncthreads();
            for (int off = 1; off < 256; off <<= 1) {
                int u = (t >= off) ? cnt[t - off] : 0;
                __syncthreads();
                cnt[t] += u;
                __syncthreads();
            }
            int node = node0 + t;
            if (node < N) {
                dinv[node] = rsqrtf(fmaxf((float)v, 1.0f));
                rs[node] = base + cnt[t];
            }
            ofs[t] = base + cnt[t] - v;
            __syncthreads();
            for (int i = base + t; i < endb; i += 256) {
                int2 rec = tmp[i];
                int pos = atomicAdd(&ofs[rec.y & 255], 1);
                ssrc[pos] = rec.x;
            }
            __syncthreads();
        }
    }
    // no grid sync between P4 and P5: gemm1 reads only x/W1

    // ---- P5: gemm1 — h[N,128](bf16) = x @ W1, MFMA, 2 column-halves -------
    if (INPH(5)) {
        u16* Wl = (u16*)smem;  // [64][136] bf16, 17408 B
        int wave = t >> 6, lane = t & 63;
        int quad = lane >> 4, ln = lane & 15;
        int ntile = (N + 63) / 64;
        const float4* Wg4 = (const float4*)W1;
        for (int half = 0; half < 2; ++half) {
            __syncthreads();
            for (int g = t; g < 64 * 32; g += 256) {
                int k = g >> 4, nq = g & 15;
                float4 v = Wg4[k * 32 + half * 16 + nq];
                int n4 = nq * 4;
                Wl[(n4 + 0) * 136 + k] = bf16rn(v.x);
                Wl[(n4 + 1) * 136 + k] = bf16rn(v.y);
                Wl[(n4 + 2) * 136 + k] = bf16rn(v.z);
                Wl[(n4 + 3) * 136 + k] = bf16rn(v.w);
            }
            __syncthreads();
            for (int tile = blockIdx.x; tile < ntile; tile += nbk) {
                int rowbase = tile * 64 + wave * 16;
                int rclamp = min(rowbase + ln, N - 1);
                f32x4 acc[4];
                #pragma unroll
                for (int ct = 0; ct < 4; ++ct) acc[ct] = (f32x4){0.f, 0.f, 0.f, 0.f};
                #pragma unroll
                for (int q = 0; q < 4; ++q) {
                    const float4* xr =
                        (const float4*)(x + (size_t)rclamp * 128 + q * 32 + quad * 8);
                    float4 a0 = xr[0], a1 = xr[1];
                    bf16x8 afr;
                    afr[0] = (short)bf16rn(a0.x); afr[1] = (short)bf16rn(a0.y);
                    afr[2] = (short)bf16rn(a0.z); afr[3] = (short)bf16rn(a0.w);
                    afr[4] = (short)bf16rn(a1.x); afr[5] = (short)bf16rn(a1.y);
                    afr[6] = (short)bf16rn(a1.z); afr[7] = (short)bf16rn(a1.w);
                    #pragma unroll
                    for (int ct = 0; ct < 4; ++ct) {
                        bf16x8 bfr =
                            *(const bf16x8*)&Wl[(ct * 16 + ln) * 136 + q * 32 + quad * 8];
                        acc[ct] = __builtin_amdgcn_mfma_f32_16x16x32_bf16(
                            afr, bfr, acc[ct], 0, 0, 0);
                    }
                }
                #pragma unroll
                for (int i = 0; i < 4; ++i) {
                    int r = rowbase + quad * 4 + i;
                    if (r < N) {
                        u16* hp = h + (size_t)r * 128 + half * 64 + ln;
                        #pragma unroll
                        for (int ct = 0; ct < 4; ++ct)
                            hp[ct * 16] = bf16rn(acc[ct][i]);
                    }
                }
            }
        }
    }
    GSYNC(6);

    // ---- P6: pull1 — out1[n,:] (bf16x2) = sum_e w_e * h[src_e,:] ----------
    if (INPH(6)) {
        int wave = t >> 6, lane = t & 63;
        const uint32* hu = (const uint32*)h;
        int ngrp = (N + 3) >> 2;
        for (int g = blockIdx.x; g < ngrp; g += nbk) {
            int n = g * 4 + wave;
            if (n >= N) continue;
            int start = __builtin_amdgcn_readfirstlane((n == 0) ? 0 : rs[n - 1]);
            int end   = __builtin_amdgcn_readfirstlane(rs[n]);
            float dn = dinv[n];
            float2 a[8];
            #pragma unroll
            for (int i = 0; i < 8; ++i) a[i] = (float2){0.f, 0.f};
            int j = start;
            for (; j + 7 < end; j += 8) {
                int si[8];
                uint32 u[8];
                float w[8];
                #pragma unroll
                for (int i = 0; i < 8; ++i)
                    si[i] = __builtin_amdgcn_readfirstlane(ssrc[j + i]);
                #pragma unroll
                for (int i = 0; i < 8; ++i)
                    u[i] = hu[(size_t)si[i] * 64 + lane];
                #pragma unroll
                for (int i = 0; i < 8; ++i)
                    w[i] = dn * dinv[si[i]];
                #pragma unroll
                for (int i = 0; i < 8; ++i)
                    bffma(a[i], w[i], u[i]);
            }
            for (; j < end; ++j) {
                int s0 = __builtin_amdgcn_readfirstlane(ssrc[j]);
                bffma(a[0], dn * dinv[s0], hu[(size_t)s0 * 64 + lane]);
            }
            float rx = ((a[0].x + a[1].x) + (a[2].x + a[3].x)) +
                       ((a[4].x + a[5].x) + (a[6].x + a[7].x));
            float ry = ((a[0].y + a[1].y) + (a[2].y + a[3].y)) +
                       ((a[4].y + a[5].y) + (a[6].y + a[7].y));
            out1[(size_t)n * 64 + lane] = ((uint32)bf16rn(ry) << 16) | bf16rn(rx);
        }
    }
    GSYNC(7);

    // ---- P7: gemm2 — h2[N,16](bf16, aliases h) = relu(out1+b1) @ W2 -------
    if (INPH(7)) {
        float* W2T = (float*)smem;            // [16][132] = 8448 B
        float* b1l = W2T + 16 * 132;          // 512 B
        float4* al4 = (float4*)(b1l + 128);   // [32][33] = 16896 B
        u16* h2 = h;
        for (int g = t; g < 2048; g += 256) {
            int k = g >> 4, f = g & 15;
            W2T[f * 132 + k] = W2[g];
        }
        if (t < 128) b1l[t] = b1[t];
        __syncthreads();

        int f = t & 15, r0 = t >> 4;
        const float4* W4 = (const float4*)W2T;  // pitch 33
        const uint4* o4 = (const uint4*)out1;
        int ntile = (N + 31) / 32;
        for (int tile = blockIdx.x; tile < ntile; tile += nbk) {
            int row0 = tile * 32;
            for (int g = t; g < 32 * 16; g += 256) {
                int r = g >> 4, k8 = g & 15;
                uint4 u = {0u, 0u, 0u, 0u};
                if (row0 + r < N) u = o4[(size_t)(row0 + r) * 16 + k8];
                const float* bb = &b1l[k8 * 8];
                float4 v0, v1;
                v0.x = fmaxf(__uint_as_float(u.x << 16)         + bb[0], 0.f);
                v0.y = fmaxf(__uint_as_float(u.x & 0xffff0000u) + bb[1], 0.f);
                v0.z = fmaxf(__uint_as_float(u.y << 16)         + bb[2], 0.f);
                v0.w = fmaxf(__uint_as_float(u.y & 0xffff0000u) + bb[3], 0.f);
                v1.x = fmaxf(__uint_as_float(u.z << 16)         + bb[4], 0.f);
                v1.y = fmaxf(__uint_as_float(u.z & 0xffff0000u) + bb[5], 0.f);
                v1.z = fmaxf(__uint_as_float(u.w << 16)         + bb[6], 0.f);
                v1.w = fmaxf(__uint_as_float(u.w & 0xffff0000u) + bb[7], 0.f);
                al4[r * 33 + k8 * 2]     = v0;
                al4[r * 33 + k8 * 2 + 1] = v1;
            }
            __syncthreads();
            float acc0 = 0.f, acc1 = 0.f;
            #pragma unroll 8
            for (int k4 = 0; k4 < 32; ++k4) {
                float4 w  = W4[f * 33 + k4];
                float4 x0 = al4[r0 * 33 + k4];
                float4 x1 = al4[(r0 + 16) * 33 + k4];
                acc0 = fmaf(x0.x, w.x, acc0); acc0 = fmaf(x0.y, w.y, acc0);
                acc0 = fmaf(x0.z, w.z, acc0); acc0 = fmaf(x0.w, w.w, acc0);
                acc1 = fmaf(x1.x, w.x, acc1); acc1 = fmaf(x1.y, w.y, acc1);
                acc1 = fmaf(x1.z, w.z, acc1); acc1 = fmaf(x1.w, w.w, acc1);
            }
            if (row0 + r0 < N)      h2[(size_t)(row0 + r0) * 16 + f] = bf16rn(acc0);
            if (row0 + r0 + 16 < N) h2[(size_t)(row0 + r0 + 16) * 16 + f] = bf16rn(acc1);
            __syncthreads();
        }
    }
    GSYNC(8);

    // ---- P8: pull2 + log_softmax (8 lanes/row, 2 classes/lane) ------------
    if (INPH(8)) {
        const uint32* h2u = (const uint32*)h;
        for (int idx = gtid; idx < N * 8; idx += gsz) {
            int n = idx >> 3;
            int c = idx & 7;
            int start = (n == 0) ? 0 : rs[n - 1];
            int end = rs[n];
            float dn = dinv[n];
            float acc0 = 0.f, acc1 = 0.f;
            for (int j = start; j < end; ++j) {
                int s = ssrc[j];
                float w = dn * dinv[s];
                uint32 u = h2u[(size_t)s * 8 + c];
                acc0 = fmaf(w, __uint_as_float(u << 16), acc0);
                acc1 = fmaf(w, __uint_as_float(u & 0xffff0000u), acc1);
            }
            float v0 = acc0 + b2[2 * c];
            float v1 = acc1 + b2[2 * c + 1];
            float m = fmaxf(v0, v1);
            #pragma unroll
            for (int off = 1; off < 8; off <<= 1) m = fmaxf(m, __shfl_xor(m, off));
            float s = expf(v0 - m) + expf(v1 - m);
            #pragma unroll
            for (int off = 1; off < 8; off <<= 1) s += __shfl_xor(s, off);
            float ls = logf(s);
            float2 r = {v0 - m - ls, v1 - m - ls};
            ((float2*)outp)[(size_t)n * 8 + c] = r;
        }
    }
    #undef INPH
    #undef GSYNC
}

extern "C" void kernel_launch(void* const* d_in, const int* in_sizes, int n_in,
                              void* d_out, int out_size, void* d_ws, size_t ws_size,
                              hipStream_t stream) {
    const float* x  = (const float*)d_in[0];
    const int*   ei = (const int*)d_in[1];
    const float* W1 = (const float*)d_in[2];
    const float* b1 = (const float*)d_in[3];
    const float* W2 = (const float*)d_in[4];
    const float* b2 = (const float*)d_in[5];
    float* outp = (float*)d_out;

    const int E = in_sizes[1] / 2;
    const int N = in_sizes[0] / 128;
    const int NB = (N + 255) >> 8;
    const int* src  = ei;
    const int* dstv = ei + E;

    const int Npad = (N + 255) & ~255;
    const int Epad = (E + 255) & ~255;
    int*   bcnt  = (int*)d_ws;                 // [NBMAX]
    int*   bbase = bcnt + NBMAX;               // [NBMAX+1] (+pad)
    int*   bfill = bbase + NBMAX + 256;        // [NBMAX]
    int*   rs    = bfill + NBMAX;              // [Npad]
    float* dinv  = (float*)(rs + Npad);        // [Npad]
    int2*  tmp   = (int2*)(dinv + Npad);       // [Epad]
    int*   ssrc  = (int*)(tmp + Epad);         // [Epad]
    u16*   h     = (u16*)(ssrc + Epad);        // N*128 bf16 (aliased as h2)
    uint32* out1 = (uint32*)(h + (size_t)N * 128);  // N*64 packed bf16x2

    // Host-side, capture-safe, deterministic queries.
    int dev = 0;
    hipGetDevice(&dev);
    int coop = 0;
    hipDeviceGetAttribute(&coop, hipDeviceAttributeCooperativeLaunch, dev);
    int numCU = 0;
    hipDeviceGetAttribute(&numCU, hipDeviceAttributeMultiprocessorCount, dev);
    int maxB = 0;
    hipOccupancyMaxActiveBlocksPerMultiprocessor(&maxB, k_mega, 256, 0);

    if (coop && maxB >= 1 && numCU >= 1) {
        int gridB = maxB * numCU;
        if (gridB > 2048) gridB = 2048;
        int p0 = 0, p1 = 8;
        void* args[] = {
            (void*)&x, (void*)&src, (void*)&dstv,
            (void*)&W1, (void*)&b1, (void*)&W2, (void*)&b2,
            (void*)&bcnt, (void*)&bbase, (void*)&bfill,
            (void*)&rs, (void*)&dinv, (void*)&tmp, (void*)&ssrc,
            (void*)&h, (void*)&out1, (void*)&outp,
            (void*)&N, (void*)&E, (void*)&NB, (void*)&p0, (void*)&p1,
        };
        hipLaunchCooperativeKernel((const void*)k_mega, dim3(gridB), dim3(256),
                                   args, 0, stream);
    } else {
        // Fallback: one ordinary launch per phase; stream order is the barrier.
        const int nchunk = (E + CHUNK - 1) / CHUNK;
        #define LP(ph, g) k_mega<<<(g), 256, 0, stream>>>( \
            x, src, dstv, W1, b1, W2, b2, bcnt, bbase, bfill, rs, dinv, tmp, \
            ssrc, h, out1, outp, N, E, NB, (ph), (ph))
        LP(0, 64);
        LP(1, 512);
        LP(2, 1);
        LP(3, nchunk);
        LP(4, NB);
        LP(5, (N + 63) / 64);
        LP(6, (N + 3) / 4);
        LP(7, (N + 31) / 32);
        LP(8, (N * 8 + 255) / 256);
        #undef LP
    }
}

// Round 9
// 200.050 us; speedup vs baseline: 2.6775x; 2.6775x over previous
//
#include <hip/hip_runtime.h>

// GCN 2-layer forward — multi-launch (grid.sync measured ~60-80us/sync on
// 8-XCD gfx950 in R8: coop mega-kernel 722us vs ~90us of work. Launch
// boundaries ARE the cheap barrier).
// R9: 10 -> 7 dispatches:
//   L1 k_combo   : gemm1 (MFMA bf16, blocks [0,ntile)) || hist partials
//                  (blocks [ntile,ntile+NH), per-block slice, no atomics,
//                  no memset needed)
//   L2 k_scanB   : reduce partials -> exclusive bucket scan, zero bfill
//   L3 k_partition, L4 k_bsort : counting sort of edges by dst
//   L5 k_pull1   : out1 (bf16x2) = normalized gather-sum of h rows, 8-unroll
//   L6 k_gemm2   : h2 = relu(out1+b1) @ W2 (bf16 out)
//   L7 k_pull2   : layer-2 gather + fused log_softmax

typedef unsigned int uint32;
typedef unsigned short u16;
typedef __attribute__((ext_vector_type(8))) short bf16x8;
typedef __attribute__((ext_vector_type(4))) float f32x4;

#define NBMAX 1024
#define CHUNK 4096
#define EH 8192   // edges per hist block

__device__ inline u16 bf16rn(float f) {
    unsigned u = __float_as_uint(f);
    return (u16)((u + 0x7fffu + ((u >> 16) & 1u)) >> 16);
}

__device__ inline void bffma(float2& a, float w, uint32 u) {
    a.x = fmaf(w, __uint_as_float(u << 16), a.x);
    a.y = fmaf(w, __uint_as_float(u & 0xffff0000u), a.y);
}

// ---- L1: gemm1 tiles || hist partial histograms ---------------------------
__global__ __launch_bounds__(256) void k_combo(
    const float* __restrict__ x, const float* __restrict__ W1,
    const int* __restrict__ dstv, int* __restrict__ partials,
    u16* __restrict__ h, int N, int E, int NB, int ntile)
{
    __shared__ __align__(16) unsigned char smem[128 * 136 * 2];  // 34816 B
    int t = threadIdx.x;

    if ((int)blockIdx.x >= ntile) {
        // ---- hist partials: block hb covers edges [hb*EH, hb*EH+EH) -------
        int* hl = (int*)smem;
        int hb = blockIdx.x - ntile;
        int e0 = hb * EH, e1 = min(e0 + EH, E);
        for (int i = t; i < NB; i += 256) hl[i] = 0;
        __syncthreads();
        for (int e = e0 + t; e < e1; e += 256)
            atomicAdd(&hl[dstv[e] >> 8], 1);
        __syncthreads();
        int* pr = partials + (size_t)hb * NBMAX;
        for (int i = t; i < NB; i += 256) pr[i] = hl[i];
        return;
    }

    // ---- gemm1: h[N,128](bf16) = x @ W1, MFMA 16x16x32, W1 staged once ----
    u16* Wl = (u16*)smem;  // [n][k] pitch 136 (2-way bank aliasing: free)
    const float4* Wg4 = (const float4*)W1;
    for (int g = t; g < 128 * 32; g += 256) {
        int k = g >> 5, n4 = (g & 31) * 4;
        float4 v = Wg4[g];
        Wl[(n4 + 0) * 136 + k] = bf16rn(v.x);
        Wl[(n4 + 1) * 136 + k] = bf16rn(v.y);
        Wl[(n4 + 2) * 136 + k] = bf16rn(v.z);
        Wl[(n4 + 3) * 136 + k] = bf16rn(v.w);
    }
    __syncthreads();

    int wave = t >> 6, lane = t & 63;
    int quad = lane >> 4, ln = lane & 15;
    int rowbase = blockIdx.x * 64 + wave * 16;
    int rclamp = min(rowbase + ln, N - 1);

    f32x4 acc[8];
    #pragma unroll
    for (int ct = 0; ct < 8; ++ct) acc[ct] = (f32x4){0.f, 0.f, 0.f, 0.f};

    #pragma unroll
    for (int q = 0; q < 4; ++q) {
        const float4* xr = (const float4*)(x + (size_t)rclamp * 128 + q * 32 + quad * 8);
        float4 a0 = xr[0], a1 = xr[1];
        bf16x8 afr;
        afr[0] = (short)bf16rn(a0.x); afr[1] = (short)bf16rn(a0.y);
        afr[2] = (short)bf16rn(a0.z); afr[3] = (short)bf16rn(a0.w);
        afr[4] = (short)bf16rn(a1.x); afr[5] = (short)bf16rn(a1.y);
        afr[6] = (short)bf16rn(a1.z); afr[7] = (short)bf16rn(a1.w);
        #pragma unroll
        for (int ct = 0; ct < 8; ++ct) {
            bf16x8 bfr = *(const bf16x8*)&Wl[(ct * 16 + ln) * 136 + q * 32 + quad * 8];
            acc[ct] = __builtin_amdgcn_mfma_f32_16x16x32_bf16(afr, bfr, acc[ct], 0, 0, 0);
        }
    }
    #pragma unroll
    for (int i = 0; i < 4; ++i) {
        int r = rowbase + quad * 4 + i;
        if (r < N) {
            u16* hp = h + (size_t)r * 128 + ln;
            #pragma unroll
            for (int ct = 0; ct < 8; ++ct)
                hp[ct * 16] = bf16rn(acc[ct][i]);
        }
    }
}

// ---- L2: reduce partials, exclusive scan, zero bfill ----------------------
__global__ __launch_bounds__(1024) void k_scanB(
    const int* __restrict__ partials, int* __restrict__ bbase,
    int* __restrict__ bfill, int NB, int E, int NH)
{
    __shared__ int s[1024];
    int t = threadIdx.x;
    int v = 0;
    if (t < NB)
        for (int p = 0; p < NH; ++p) v += partials[(size_t)p * NBMAX + t];
    s[t] = v;
    __syncthreads();
    for (int off = 1; off < 1024; off <<= 1) {
        int u = (t >= off) ? s[t - off] : 0;
        __syncthreads();
        s[t] += u;
        __syncthreads();
    }
    if (t < NB) {
        bbase[t] = s[t] - v;
        bfill[t] = 0;
    }
    if (t == 0) bbase[NB] = E;
}

// ---- L3: partition edges into bucket regions ------------------------------
__global__ __launch_bounds__(256) void k_partition(
    const int* __restrict__ src, const int* __restrict__ dstv,
    const int* __restrict__ bbase, int* __restrict__ bfill,
    int2* __restrict__ tmp, int E, int NB)
{
    __shared__ int cntL[NBMAX];
    __shared__ int baseL[NBMAX];
    int t = threadIdx.x;
    int e0 = blockIdx.x * CHUNK;
    int e1 = min(e0 + CHUNK, E);
    for (int i = t; i < NB; i += 256) cntL[i] = 0;
    __syncthreads();
    for (int e = e0 + t; e < e1; e += 256)
        atomicAdd(&cntL[dstv[e] >> 8], 1);
    __syncthreads();
    for (int i = t; i < NB; i += 256) {
        int cc = cntL[i];
        baseL[i] = cc ? bbase[i] + atomicAdd(&bfill[i], cc) : 0;
        cntL[i] = 0;
    }
    __syncthreads();
    for (int e = e0 + t; e < e1; e += 256) {
        int sv = src[e], d = dstv[e];
        int b = d >> 8;
        int r = atomicAdd(&cntL[b], 1);
        tmp[baseL[b] + r] = make_int2(sv, d);
    }
}

// ---- L4: per-bucket exact sort; emit dinv / rs / ssrc ---------------------
__global__ __launch_bounds__(256) void k_bsort(
    const int2* __restrict__ tmp, const int* __restrict__ bbase,
    int* __restrict__ ssrc, int* __restrict__ rs,
    float* __restrict__ dinv, int N)
{
    __shared__ int cnt[256];
    __shared__ int ofs[256];
    int t = threadIdx.x;
    int b = blockIdx.x;
    int base = bbase[b];
    int endb = bbase[b + 1];
    int node0 = b << 8;

    cnt[t] = 0;
    __syncthreads();
    for (int i = base + t; i < endb; i += 256)
        atomicAdd(&cnt[tmp[i].y & 255], 1);
    __syncthreads();
    int v = cnt[t];
    __syncthreads();
    for (int off = 1; off < 256; off <<= 1) {
        int u = (t >= off) ? cnt[t - off] : 0;
        __syncthreads();
        cnt[t] += u;
        __syncthreads();
    }
    int node = node0 + t;
    if (node < N) {
        dinv[node] = rsqrtf(fmaxf((float)v, 1.0f));
        rs[node] = base + cnt[t];
    }
    ofs[t] = base + cnt[t] - v;
    __syncthreads();
    for (int i = base + t; i < endb; i += 256) {
        int2 rec = tmp[i];
        int pos = atomicAdd(&ofs[rec.y & 255], 1);
        ssrc[pos] = rec.x;
    }
}

// ---- L5: pull1 — out1[n,:] (bf16x2) = sum_e w_e * h[src_e,:], 8-unroll ----
__global__ __launch_bounds__(256) void k_pull1(
    const int* __restrict__ rs, const int* __restrict__ ssrc,
    const float* __restrict__ dinv, const uint32* __restrict__ h,
    uint32* __restrict__ out1, int N)
{
    int n = (blockIdx.x * 256 + threadIdx.x) >> 6;
    if (n >= N) return;
    int lane = threadIdx.x & 63;
    int start = __builtin_amdgcn_readfirstlane((n == 0) ? 0 : rs[n - 1]);
    int end   = __builtin_amdgcn_readfirstlane(rs[n]);
    float dn = dinv[n];
    float2 a[8];
    #pragma unroll
    for (int i = 0; i < 8; ++i) a[i] = (float2){0.f, 0.f};
    int j = start;
    for (; j + 7 < end; j += 8) {
        int si[8];
        uint32 u[8];
        float w[8];
        #pragma unroll
        for (int i = 0; i < 8; ++i)
            si[i] = __builtin_amdgcn_readfirstlane(ssrc[j + i]);
        #pragma unroll
        for (int i = 0; i < 8; ++i)
            u[i] = h[(size_t)si[i] * 64 + lane];
        #pragma unroll
        for (int i = 0; i < 8; ++i)
            w[i] = dn * dinv[si[i]];
        #pragma unroll
        for (int i = 0; i < 8; ++i)
            bffma(a[i], w[i], u[i]);
    }
    for (; j < end; ++j) {
        int s0 = __builtin_amdgcn_readfirstlane(ssrc[j]);
        bffma(a[0], dn * dinv[s0], h[(size_t)s0 * 64 + lane]);
    }
    float rx = ((a[0].x + a[1].x) + (a[2].x + a[3].x)) +
               ((a[4].x + a[5].x) + (a[6].x + a[7].x));
    float ry = ((a[0].y + a[1].y) + (a[2].y + a[3].y)) +
               ((a[4].y + a[5].y) + (a[6].y + a[7].y));
    out1[(size_t)n * 64 + lane] = ((uint32)bf16rn(ry) << 16) | bf16rn(rx);
}

// ---- L6: gemm2 — h2[N,16](bf16) = relu(out1+b1) @ W2 ----------------------
__global__ __launch_bounds__(256) void k_gemm2(
    const uint32* __restrict__ out1, const float* __restrict__ b1,
    const float* __restrict__ W2, u16* __restrict__ h2, int N)
{
    __shared__ float W2T[16 * 132];
    __shared__ float b1l[128];
    __shared__ float al[32 * 132];
    int t = threadIdx.x;
    int row0 = blockIdx.x * 32;

    for (int g = t; g < 2048; g += 256) {
        int k = g >> 4, f = g & 15;
        W2T[f * 132 + k] = W2[g];
    }
    if (t < 128) b1l[t] = b1[t];
    __syncthreads();

    float4* al4 = (float4*)al;
    const uint4* o4 = (const uint4*)out1;
    for (int g = t; g < 32 * 16; g += 256) {
        int r = g >> 4, k8 = g & 15;
        uint4 u = {0u, 0u, 0u, 0u};
        if (row0 + r < N) u = o4[(size_t)(row0 + r) * 16 + k8];
        const float* bb = &b1l[k8 * 8];
        float4 v0, v1;
        v0.x = fmaxf(__uint_as_float(u.x << 16)         + bb[0], 0.f);
        v0.y = fmaxf(__uint_as_float(u.x & 0xffff0000u) + bb[1], 0.f);
        v0.z = fmaxf(__uint_as_float(u.y << 16)         + bb[2], 0.f);
        v0.w = fmaxf(__uint_as_float(u.y & 0xffff0000u) + bb[3], 0.f);
        v1.x = fmaxf(__uint_as_float(u.z << 16)         + bb[4], 0.f);
        v1.y = fmaxf(__uint_as_float(u.z & 0xffff0000u) + bb[5], 0.f);
        v1.z = fmaxf(__uint_as_float(u.w << 16)         + bb[6], 0.f);
        v1.w = fmaxf(__uint_as_float(u.w & 0xffff0000u) + bb[7], 0.f);
        al4[r * 33 + k8 * 2]     = v0;
        al4[r * 33 + k8 * 2 + 1] = v1;
    }
    __syncthreads();

    int f = t & 15, r0 = t >> 4;
    const float4* W4 = (const float4*)W2T;
    float acc0 = 0.f, acc1 = 0.f;
    #pragma unroll 8
    for (int k4 = 0; k4 < 32; ++k4) {
        float4 w  = W4[f * 33 + k4];
        float4 x0 = al4[r0 * 33 + k4];
        float4 x1 = al4[(r0 + 16) * 33 + k4];
        acc0 = fmaf(x0.x, w.x, acc0); acc0 = fmaf(x0.y, w.y, acc0);
        acc0 = fmaf(x0.z, w.z, acc0); acc0 = fmaf(x0.w, w.w, acc0);
        acc1 = fmaf(x1.x, w.x, acc1); acc1 = fmaf(x1.y, w.y, acc1);
        acc1 = fmaf(x1.z, w.z, acc1); acc1 = fmaf(x1.w, w.w, acc1);
    }
    if (row0 + r0 < N)      h2[(size_t)(row0 + r0) * 16 + f] = bf16rn(acc0);
    if (row0 + r0 + 16 < N) h2[(size_t)(row0 + r0 + 16) * 16 + f] = bf16rn(acc1);
}

// ---- L7: pull2 + log_softmax (8 lanes/row, 2 classes/lane) ----------------
__global__ __launch_bounds__(256) void k_pull2(
    const int* __restrict__ rs, const int* __restrict__ ssrc,
    const float* __restrict__ dinv, const uint32* __restrict__ h2,
    const float* __restrict__ b2, float* __restrict__ out, int N)
{
    int idx = blockIdx.x * 256 + threadIdx.x;
    int n = idx >> 3;
    if (n >= N) return;
    int c = idx & 7;
    int start = (n == 0) ? 0 : rs[n - 1];
    int end = rs[n];
    float dn = dinv[n];
    float acc0 = 0.f, acc1 = 0.f;
    for (int j = start; j < end; ++j) {
        int s = ssrc[j];
        float w = dn * dinv[s];
        uint32 u = h2[(size_t)s * 8 + c];
        acc0 = fmaf(w, __uint_as_float(u << 16), acc0);
        acc1 = fmaf(w, __uint_as_float(u & 0xffff0000u), acc1);
    }
    float v0 = acc0 + b2[2 * c];
    float v1 = acc1 + b2[2 * c + 1];
    float m = fmaxf(v0, v1);
    #pragma unroll
    for (int off = 1; off < 8; off <<= 1) m = fmaxf(m, __shfl_xor(m, off));
    float s = expf(v0 - m) + expf(v1 - m);
    #pragma unroll
    for (int off = 1; off < 8; off <<= 1) s += __shfl_xor(s, off);
    float ls = logf(s);
    float2 r = {v0 - m - ls, v1 - m - ls};
    ((float2*)out)[(size_t)n * 8 + c] = r;
}

extern "C" void kernel_launch(void* const* d_in, const int* in_sizes, int n_in,
                              void* d_out, int out_size, void* d_ws, size_t ws_size,
                              hipStream_t stream) {
    const float* x  = (const float*)d_in[0];
    const int*   ei = (const int*)d_in[1];
    const float* W1 = (const float*)d_in[2];
    const float* b1 = (const float*)d_in[3];
    const float* W2 = (const float*)d_in[4];
    const float* b2 = (const float*)d_in[5];
    float* outp = (float*)d_out;

    const int E = in_sizes[1] / 2;
    const int N = in_sizes[0] / 128;
    const int NB = (N + 255) >> 8;
    const int NH = (E + EH - 1) / EH;
    const int ntile = (N + 63) / 64;
    const int* src  = ei;
    const int* dstv = ei + E;

    const int Npad = (N + 255) & ~255;
    const int Epad = (E + 255) & ~255;
    int*   partials = (int*)d_ws;                   // [NH(<=128)][NBMAX]
    int*   bbase = partials + 128 * NBMAX;          // [NBMAX+1] (+pad)
    int*   bfill = bbase + NBMAX + 256;             // [NBMAX]
    int*   rs    = bfill + NBMAX;                   // [Npad]
    float* dinv  = (float*)(rs + Npad);             // [Npad]
    int2*  tmp   = (int2*)(dinv + Npad);            // [Epad]
    int*   ssrc  = (int*)(tmp + Epad);              // [Epad]
    u16*   h     = (u16*)(ssrc + Epad);             // N*128 bf16 (aliased h2)
    uint32* out1 = (uint32*)(h + (size_t)N * 128);  // N*64 packed bf16x2
    u16*   h2    = h;

    k_combo<<<ntile + NH, 256, 0, stream>>>(x, W1, dstv, partials, h, N, E, NB, ntile);
    k_scanB<<<1, 1024, 0, stream>>>(partials, bbase, bfill, NB, E, NH);
    k_partition<<<(E + CHUNK - 1) / CHUNK, 256, 0, stream>>>(src, dstv, bbase,
                                                             bfill, tmp, E, NB);
    k_bsort<<<NB, 256, 0, stream>>>(tmp, bbase, ssrc, rs, dinv, N);
    k_pull1<<<(N * 64 + 255) / 256, 256, 0, stream>>>(rs, ssrc, dinv,
                                                      (const uint32*)h, out1, N);
    k_gemm2<<<(N + 31) / 32, 256, 0, stream>>>(out1, b1, W2, h2, N);
    k_pull2<<<(N * 8 + 255) / 256, 256, 0, stream>>>(rs, ssrc, dinv,
                                                     (const uint32*)h2, b2, outp, N);
}